// Round 7
// baseline (252.121 us; speedup 1.0000x reference)
//
#include <hip/hip_runtime.h>
#include <hip/hip_fp16.h>

// Problem constants: B=2, CIN=32, COUT=64, K=9, H=256, W=512, OH=256, OW=512
#define HW_IN   131072
#define W_IN    512
#define H_IN    256
#define HW_OUT  131072
#define CIN     32
#define COUT    64
#define KK      9
#define BB      2

typedef _Float16 hf2 __attribute__((ext_vector_type(2)));
typedef _Float16 hf4 __attribute__((ext_vector_type(4)));
typedef _Float16 hf8 __attribute__((ext_vector_type(8)));
typedef float f32x4 __attribute__((ext_vector_type(4)));

static __device__ __forceinline__ hf8 u4h(uint4 u) {
  return __builtin_bit_cast(hf8, u);
}

// ---------------------------------------------------------------------------
// Kernel 1: transpose x (B,CIN,H*W) fp32 -> xt (H*W, B, CIN) f16, via LDS.
// ~5us (R3 single-dispatch run proved the ~88-95us per-round residual is
// FIXED harness overhead). 1KB-contiguous plane-row reads, LDS turn,
// 1KB-contiguous record stores.
// ---------------------------------------------------------------------------
__global__ __launch_bounds__(256) void transpose_lds(
    const float* __restrict__ x, _Float16* __restrict__ xt) {
  __shared__ _Float16 lt[64][260];   // 33.3 KB, row stride 520B
  int t = threadIdx.x;
  int wave = t >> 6, lane = t & 63;
  int hwbase = blockIdx.x * 256;

#pragma unroll
  for (int i = 0; i < 16; ++i) {
    int p = i * 4 + wave;
    f32x4 v = *((const f32x4*)(x + (size_t)p * HW_IN + hwbase) + lane);
    hf4 h;
    h[0] = (_Float16)v[0]; h[1] = (_Float16)v[1];
    h[2] = (_Float16)v[2]; h[3] = (_Float16)v[3];
    *(hf4*)&lt[p][lane * 4] = h;
  }
  __syncthreads();

  int gg  = t & 7;
  int hl0 = t >> 3;
#pragma unroll
  for (int j = 0; j < 8; ++j) {
    int hwl = hl0 + j * 32;
    hf8 h;
#pragma unroll
    for (int c = 0; c < 8; ++c) h[c] = lt[gg * 8 + c][hwl];
    *(hf8*)(xt + (size_t)(hwbase + hwl) * 64 + gg * 8) = h;
  }
}

// ---------------------------------------------------------------------------
// Kernel 2: batch-paired gather + MFMA. R7 occupancy fix done right:
// R5 proved 32 waves/CU lifts achieved BW 3.13->3.95 TB/s, but its
// (1024,8) bounds squeezed the kernel to 32 VGPR, serializing the corner
// loads (FETCH 246->441MB). The kernel needs only 60 VGPR (R4/R6 measured)
// which ALREADY satisfies the <=64 cap of 8 waves/SIMD -- occupancy was
// LDS-capped, not register-capped: 36KB per 256-thread block = 4 blocks/CU
// x 4 waves = 16 waves/CU. Fix: 512-thread blocks (8 waves) share one 36KB
// stage -> 4 blocks/CU (144KB LDS, 2048 threads = CU max) = 32 waves/CU
// with the per-wave inner loop byte-identical to R4.
// ---------------------------------------------------------------------------
__global__ __launch_bounds__(512, 8) void mapped_conv_mfma(
    const _Float16* __restrict__ xt,
    const float* __restrict__ weight,   // [COUT][CIN][KK] fp32
    const float* __restrict__ bias,     // [COUT]
    const float* __restrict__ sm,       // [HW_OUT][KK][2] fp32
    float* __restrict__ out) {          // [BB][COUT][HW_OUT] fp32
  __shared__ __align__(16) _Float16 w_lds[KK * COUT * CIN];  // 36 KB

  int t = threadIdx.x;
  // Stage weights: w_lds[(k*64 + o)*32 + c] = W[o][c][k] as f16.
  for (int j = t; j < COUT * CIN * KK; j += 512) {
    unsigned ju = (unsigned)j;
    unsigned o  = ju / 288u;
    unsigned rr = ju % 288u;
    unsigned c  = rr / 9u;
    unsigned k  = rr % 9u;
    w_lds[(k * 64u + o) * 32u + c] = (_Float16)weight[ju];
  }
  __syncthreads();

  int wave = t >> 6;      // 0..7
  int lane = t & 63;
  int m    = lane & 15;   // A-row: pixel; B-col: cout within N-tile
  int quad = lane >> 4;   // channel quarter (A) / k-chunk (B) / row group (C)

  int hw_base = blockIdx.x * 128 + wave * 16;     // 1024 blocks x 8 waves
  int hw = hw_base + m;

  const uint4* xt4 = (const uint4*)xt;

  f32x4 acc0[4] = {{0.f,0.f,0.f,0.f},{0.f,0.f,0.f,0.f},
                   {0.f,0.f,0.f,0.f},{0.f,0.f,0.f,0.f}};
  f32x4 acc1[4] = {{0.f,0.f,0.f,0.f},{0.f,0.f,0.f,0.f},
                   {0.f,0.f,0.f,0.f},{0.f,0.f,0.f,0.f}};

  const float* smp = sm + (size_t)hw * (KK * 2);
  const uint4* wbl = (const uint4*)w_lds + (size_t)(m * 4 + quad);

#pragma unroll 2
  for (int k = 0; k < KK; ++k) {
    float sx = smp[k * 2 + 0];
    float sy = smp[k * 2 + 1];
    float bxf = floorf(sx), byf = floorf(sy);
    float fx = sx - bxf, fy = sy - byf;
    int ix0 = (int)bxf, iy0 = (int)byf;
    int ix1 = min(ix0 + 1, W_IN - 1);
    int iy1 = min(iy0 + 1, H_IN - 1);
    ix0 = max(min(ix0, W_IN - 1), 0); ix1 = max(ix1, 0);
    iy0 = max(min(iy0, H_IN - 1), 0); iy1 = max(iy1, 0);

    int r00 = (iy0 * W_IN + ix0) * 8;
    int r01 = (iy0 * W_IN + ix1) * 8;
    int r10 = (iy1 * W_IN + ix0) * 8;
    int r11 = (iy1 * W_IN + ix1) * 8;

    // b0 half (granule quad) and b1 half (granule 4+quad) back-to-back:
    // same 128B record; (ix0,ix1) pair makes 2x256B contiguous chunks.
    uint4 v00a = xt4[r00 + quad],     v00b = xt4[r00 + 4 + quad];
    uint4 v01a = xt4[r01 + quad],     v01b = xt4[r01 + 4 + quad];
    uint4 v10a = xt4[r10 + quad],     v10b = xt4[r10 + 4 + quad];
    uint4 v11a = xt4[r11 + quad],     v11b = xt4[r11 + 4 + quad];

    _Float16 w00 = (_Float16)((1.f - fx) * (1.f - fy));
    _Float16 w01 = (_Float16)(fx * (1.f - fy));
    _Float16 w10 = (_Float16)((1.f - fx) * fy);
    _Float16 w11 = (_Float16)(fx * fy);
    hf8 h00 = {w00, w00, w00, w00, w00, w00, w00, w00};
    hf8 h01 = {w01, w01, w01, w01, w01, w01, w01, w01};
    hf8 h10 = {w10, w10, w10, w10, w10, w10, w10, w10};
    hf8 h11 = {w11, w11, w11, w11, w11, w11, w11, w11};

    hf8 a0 = h00 * u4h(v00a) + h01 * u4h(v01a) + h10 * u4h(v10a) + h11 * u4h(v11a);
    hf8 a1 = h00 * u4h(v00b) + h01 * u4h(v01b) + h10 * u4h(v10b) + h11 * u4h(v11b);

    const uint4* wk = wbl + (size_t)k * 256;   // per-k block = 64 o * 4 granules
    hf8 b0 = u4h(wk[0]);
    hf8 b1 = u4h(wk[64]);
    hf8 b2 = u4h(wk[128]);
    hf8 b3 = u4h(wk[192]);

    acc0[0] = __builtin_amdgcn_mfma_f32_16x16x32_f16(a0, b0, acc0[0], 0, 0, 0);
    acc1[0] = __builtin_amdgcn_mfma_f32_16x16x32_f16(a1, b0, acc1[0], 0, 0, 0);
    acc0[1] = __builtin_amdgcn_mfma_f32_16x16x32_f16(a0, b1, acc0[1], 0, 0, 0);
    acc1[1] = __builtin_amdgcn_mfma_f32_16x16x32_f16(a1, b1, acc1[1], 0, 0, 0);
    acc0[2] = __builtin_amdgcn_mfma_f32_16x16x32_f16(a0, b2, acc0[2], 0, 0, 0);
    acc1[2] = __builtin_amdgcn_mfma_f32_16x16x32_f16(a1, b2, acc1[2], 0, 0, 0);
    acc0[3] = __builtin_amdgcn_mfma_f32_16x16x32_f16(a0, b3, acc0[3], 0, 0, 0);
    acc1[3] = __builtin_amdgcn_mfma_f32_16x16x32_f16(a1, b3, acc1[3], 0, 0, 0);
  }

  // Epilogue: lane writes 4 consecutive pixels (rows quad*4..+3) for cout n,
  // both batches. Plain stores (L2 write-combined; NT doubled WRITE in R5).
  int hw0 = hw_base + quad * 4;
#pragma unroll
  for (int nt = 0; nt < 4; ++nt) {
    int n = nt * 16 + m;
    float bn = bias[n];
    float4 v0 = make_float4(acc0[nt][0] + bn, acc0[nt][1] + bn,
                            acc0[nt][2] + bn, acc0[nt][3] + bn);
    float4 v1 = make_float4(acc1[nt][0] + bn, acc1[nt][1] + bn,
                            acc1[nt][2] + bn, acc1[nt][3] + bn);
    *(float4*)(out + (size_t)n * HW_OUT + hw0) = v0;
    *(float4*)(out + (size_t)(COUT + n) * HW_OUT + hw0) = v1;
  }
}

extern "C" void kernel_launch(void* const* d_in, const int* in_sizes, int n_in,
                              void* d_out, int out_size, void* d_ws, size_t ws_size,
                              hipStream_t stream) {
  const float* x  = (const float*)d_in[0];   // [B][CIN][H*W]
  const float* w  = (const float*)d_in[1];   // [COUT][CIN][KK]
  const float* bs = (const float*)d_in[2];   // [COUT]
  const float* sm = (const float*)d_in[3];   // [OH*OW][KK][2]
  float* out = (float*)d_out;                // [B][COUT][OH*OW]
  _Float16* xt = (_Float16*)d_ws;            // 16 MB scratch: (H*W, B, CIN) f16

  transpose_lds<<<dim3(512), dim3(256), 0, stream>>>(x, xt);
  mapped_conv_mfma<<<dim3(1024), dim3(512), 0, stream>>>(xt, w, bs, sm, out);
}

// Round 8
// 195.161 us; speedup vs baseline: 1.2919x; 1.2919x over previous
//
#include <hip/hip_runtime.h>
#include <hip/hip_fp16.h>

// Problem constants: B=2, CIN=32, COUT=64, K=9, H=256, W=512, OH=256, OW=512
#define HW_IN   131072
#define W_IN    512
#define H_IN    256
#define HW_OUT  131072
#define CIN     32
#define COUT    64
#define KK      9
#define BB      2

typedef _Float16 hf2 __attribute__((ext_vector_type(2)));
typedef _Float16 hf4 __attribute__((ext_vector_type(4)));
typedef _Float16 hf8 __attribute__((ext_vector_type(8)));
typedef float f32x4 __attribute__((ext_vector_type(4)));

static __device__ __forceinline__ hf8 u4h(uint4 u) {
  return __builtin_bit_cast(hf8, u);
}

// ---------------------------------------------------------------------------
// Kernel 1: transpose x (B,CIN,H*W) fp32 -> xt (H*W, B, CIN) f16, via LDS.
// ~5us (R3 single-dispatch run proved the ~85-95us per-round residual is
// FIXED harness overhead). 1KB-contiguous plane-row reads, LDS turn,
// 1KB-contiguous record stores.
// ---------------------------------------------------------------------------
__global__ __launch_bounds__(256) void transpose_lds(
    const float* __restrict__ x, _Float16* __restrict__ xt) {
  __shared__ _Float16 lt[64][260];   // 33.3 KB, row stride 520B
  int t = threadIdx.x;
  int wave = t >> 6, lane = t & 63;
  int hwbase = blockIdx.x * 256;

#pragma unroll
  for (int i = 0; i < 16; ++i) {
    int p = i * 4 + wave;
    f32x4 v = *((const f32x4*)(x + (size_t)p * HW_IN + hwbase) + lane);
    hf4 h;
    h[0] = (_Float16)v[0]; h[1] = (_Float16)v[1];
    h[2] = (_Float16)v[2]; h[3] = (_Float16)v[3];
    *(hf4*)&lt[p][lane * 4] = h;
  }
  __syncthreads();

  int gg  = t & 7;
  int hl0 = t >> 3;
#pragma unroll
  for (int j = 0; j < 8; ++j) {
    int hwl = hl0 + j * 32;
    hf8 h;
#pragma unroll
    for (int c = 0; c < 8; ++c) h[c] = lt[gg * 8 + c][hwl];
    *(hf8*)(xt + (size_t)(hwbase + hwl) * 64 + gg * 8) = h;
  }
}

// ---------------------------------------------------------------------------
// Kernel 2: batch-paired gather + MFMA, R8 = R4 clean config + y-windowed
// two-pass tap loop.
// R5/R7 proved 32 waves/CU is register-impossible (92 unified regs x 32 =
// 2944 > 2048 pool; the forced 64-reg budget spills + serializes loads,
// FETCH 246->434MB). So stay at the clean 16-wave point and attack TRAFFIC:
// xt gather demand 604MB vs FETCH 246MB = ~59% L2 hit, capacity-limited
// (per-XCD L2 4MB holds 1/4 of the 16MB xt). Pass 0 handles taps with
// iy0<128 (rows 0..128, ~8MB footprint), pass 1 the rest: per-pass
// footprint halves -> hit rate up, average gather latency down (more
// 200cyc L2 hits). Cost: 18 tap-iterations (MFMA x2 at 3.7% util, VALU
// 23->~40% -- both have headroom). Inactive lanes exec-mask their loads;
// corner regs zero-init so inactive taps contribute exactly 0.
// ---------------------------------------------------------------------------
__global__ __launch_bounds__(256, 4) void mapped_conv_mfma(
    const _Float16* __restrict__ xt,
    const float* __restrict__ weight,   // [COUT][CIN][KK] fp32
    const float* __restrict__ bias,     // [COUT]
    const float* __restrict__ sm,       // [HW_OUT][KK][2] fp32
    float* __restrict__ out) {          // [BB][COUT][HW_OUT] fp32
  __shared__ __align__(16) _Float16 w_lds[KK * COUT * CIN];  // 36 KB

  int t = threadIdx.x;
  // Stage weights: w_lds[(k*64 + o)*32 + c] = W[o][c][k] as f16.
  for (int j = t; j < COUT * CIN * KK; j += 256) {
    unsigned ju = (unsigned)j;
    unsigned o  = ju / 288u;
    unsigned rr = ju % 288u;
    unsigned c  = rr / 9u;
    unsigned k  = rr % 9u;
    w_lds[(k * 64u + o) * 32u + c] = (_Float16)weight[ju];
  }
  __syncthreads();

  int wave = t >> 6;
  int lane = t & 63;
  int m    = lane & 15;   // A-row: pixel; B-col: cout within N-tile
  int quad = lane >> 4;   // channel quarter (A) / k-chunk (B) / row group (C)

  int hw_base = blockIdx.x * 64 + wave * 16;      // 2048 blocks x 4 waves
  int hw = hw_base + m;

  const uint4* xt4 = (const uint4*)xt;

  f32x4 acc0[4] = {{0.f,0.f,0.f,0.f},{0.f,0.f,0.f,0.f},
                   {0.f,0.f,0.f,0.f},{0.f,0.f,0.f,0.f}};
  f32x4 acc1[4] = {{0.f,0.f,0.f,0.f},{0.f,0.f,0.f,0.f},
                   {0.f,0.f,0.f,0.f},{0.f,0.f,0.f,0.f}};

  const float* smp = sm + (size_t)hw * (KK * 2);
  const uint4* wbl = (const uint4*)w_lds + (size_t)(m * 4 + quad);

  // Corner buffers zero-initialized: inactive taps blend 0*0 = 0 (never
  // uninitialized-data * 0 = NaN).
  uint4 v00a = {0,0,0,0}, v00b = {0,0,0,0};
  uint4 v01a = {0,0,0,0}, v01b = {0,0,0,0};
  uint4 v10a = {0,0,0,0}, v10b = {0,0,0,0};
  uint4 v11a = {0,0,0,0}, v11b = {0,0,0,0};

#pragma unroll 1
  for (int pass = 0; pass < 2; ++pass) {
#pragma unroll 3
    for (int k = 0; k < KK; ++k) {
      float sx = smp[k * 2 + 0];
      float sy = smp[k * 2 + 1];
      float bxf = floorf(sx), byf = floorf(sy);
      float fx = sx - bxf, fy = sy - byf;
      int ix0 = (int)bxf, iy0 = (int)byf;
      int ix1 = min(ix0 + 1, W_IN - 1);
      int iy1 = min(iy0 + 1, H_IN - 1);
      ix0 = max(min(ix0, W_IN - 1), 0); ix1 = max(ix1, 0);
      iy0 = max(min(iy0, H_IN - 1), 0); iy1 = max(iy1, 0);

      // y-window membership: pass 0 = rows [0,128), pass 1 = rows [128,256).
      bool active = (pass == 0) ? (iy0 < 128) : (iy0 >= 128);
      float af = active ? 1.f : 0.f;

      if (active) {
        int r00 = (iy0 * W_IN + ix0) * 8;
        int r01 = (iy0 * W_IN + ix1) * 8;
        int r10 = (iy1 * W_IN + ix0) * 8;
        int r11 = (iy1 * W_IN + ix1) * 8;
        // b0 half (granule quad) and b1 half (granule 4+quad) back-to-back:
        // same 128B record; (ix0,ix1) pair makes 2x256B contiguous chunks.
        v00a = xt4[r00 + quad];  v00b = xt4[r00 + 4 + quad];
        v01a = xt4[r01 + quad];  v01b = xt4[r01 + 4 + quad];
        v10a = xt4[r10 + quad];  v10b = xt4[r10 + 4 + quad];
        v11a = xt4[r11 + quad];  v11b = xt4[r11 + 4 + quad];
      }

      _Float16 w00 = (_Float16)((1.f - fx) * (1.f - fy) * af);
      _Float16 w01 = (_Float16)(fx * (1.f - fy) * af);
      _Float16 w10 = (_Float16)((1.f - fx) * fy * af);
      _Float16 w11 = (_Float16)(fx * fy * af);
      hf8 h00 = {w00, w00, w00, w00, w00, w00, w00, w00};
      hf8 h01 = {w01, w01, w01, w01, w01, w01, w01, w01};
      hf8 h10 = {w10, w10, w10, w10, w10, w10, w10, w10};
      hf8 h11 = {w11, w11, w11, w11, w11, w11, w11, w11};

      hf8 a0 = h00 * u4h(v00a) + h01 * u4h(v01a) + h10 * u4h(v10a) + h11 * u4h(v11a);
      hf8 a1 = h00 * u4h(v00b) + h01 * u4h(v01b) + h10 * u4h(v10b) + h11 * u4h(v11b);

      const uint4* wk = wbl + (size_t)k * 256;   // per-k block = 64 o * 4 granules
      hf8 b0 = u4h(wk[0]);
      hf8 b1 = u4h(wk[64]);
      hf8 b2 = u4h(wk[128]);
      hf8 b3 = u4h(wk[192]);

      acc0[0] = __builtin_amdgcn_mfma_f32_16x16x32_f16(a0, b0, acc0[0], 0, 0, 0);
      acc1[0] = __builtin_amdgcn_mfma_f32_16x16x32_f16(a1, b0, acc1[0], 0, 0, 0);
      acc0[1] = __builtin_amdgcn_mfma_f32_16x16x32_f16(a0, b1, acc0[1], 0, 0, 0);
      acc1[1] = __builtin_amdgcn_mfma_f32_16x16x32_f16(a1, b1, acc1[1], 0, 0, 0);
      acc0[2] = __builtin_amdgcn_mfma_f32_16x16x32_f16(a0, b2, acc0[2], 0, 0, 0);
      acc1[2] = __builtin_amdgcn_mfma_f32_16x16x32_f16(a1, b2, acc1[2], 0, 0, 0);
      acc0[3] = __builtin_amdgcn_mfma_f32_16x16x32_f16(a0, b3, acc0[3], 0, 0, 0);
      acc1[3] = __builtin_amdgcn_mfma_f32_16x16x32_f16(a1, b3, acc1[3], 0, 0, 0);
    }
  }

  // Epilogue: lane writes 4 consecutive pixels (rows quad*4..+3) for cout n,
  // both batches. Plain stores (L2 write-combined; NT doubled WRITE in R5).
  int hw0 = hw_base + quad * 4;
#pragma unroll
  for (int nt = 0; nt < 4; ++nt) {
    int n = nt * 16 + m;
    float bn = bias[n];
    float4 v0 = make_float4(acc0[nt][0] + bn, acc0[nt][1] + bn,
                            acc0[nt][2] + bn, acc0[nt][3] + bn);
    float4 v1 = make_float4(acc1[nt][0] + bn, acc1[nt][1] + bn,
                            acc1[nt][2] + bn, acc1[nt][3] + bn);
    *(float4*)(out + (size_t)n * HW_OUT + hw0) = v0;
    *(float4*)(out + (size_t)(COUT + n) * HW_OUT + hw0) = v1;
  }
}

extern "C" void kernel_launch(void* const* d_in, const int* in_sizes, int n_in,
                              void* d_out, int out_size, void* d_ws, size_t ws_size,
                              hipStream_t stream) {
  const float* x  = (const float*)d_in[0];   // [B][CIN][H*W]
  const float* w  = (const float*)d_in[1];   // [COUT][CIN][KK]
  const float* bs = (const float*)d_in[2];   // [COUT]
  const float* sm = (const float*)d_in[3];   // [OH*OW][KK][2]
  float* out = (float*)d_out;                // [B][COUT][OH*OW]
  _Float16* xt = (_Float16*)d_ws;            // 16 MB scratch: (H*W, B, CIN) f16

  transpose_lds<<<dim3(512), dim3(256), 0, stream>>>(x, xt);
  mapped_conv_mfma<<<dim3(2048), dim3(256), 0, stream>>>(xt, w, bs, sm, out);
}

// Round 9
// 191.141 us; speedup vs baseline: 1.3190x; 1.0210x over previous
//
#include <hip/hip_runtime.h>
#include <hip/hip_fp16.h>

// Problem constants: B=2, CIN=32, COUT=64, K=9, H=256, W=512, OH=256, OW=512
#define HW_IN   131072
#define W_IN    512
#define H_IN    256
#define HW_OUT  131072
#define CIN     32
#define COUT    64
#define KK      9
#define BB      2

typedef _Float16 hf2 __attribute__((ext_vector_type(2)));
typedef _Float16 hf4 __attribute__((ext_vector_type(4)));
typedef _Float16 hf8 __attribute__((ext_vector_type(8)));
typedef float f32x4 __attribute__((ext_vector_type(4)));

static __device__ __forceinline__ hf8 u4h(uint4 u) {
  return __builtin_bit_cast(hf8, u);
}

// ---------------------------------------------------------------------------
// Kernel 1: transpose x (B,CIN,H*W) fp32 -> xt (H*W, B, CIN) f16, via LDS.
// ~5us (R3 single-dispatch run proved the ~85-95us per-round residual is
// FIXED harness overhead). 1KB-contiguous plane-row reads, LDS turn,
// 1KB-contiguous record stores.
// ---------------------------------------------------------------------------
__global__ __launch_bounds__(256) void transpose_lds(
    const float* __restrict__ x, _Float16* __restrict__ xt) {
  __shared__ _Float16 lt[64][260];   // 33.3 KB, row stride 520B
  int t = threadIdx.x;
  int wave = t >> 6, lane = t & 63;
  int hwbase = blockIdx.x * 256;

#pragma unroll
  for (int i = 0; i < 16; ++i) {
    int p = i * 4 + wave;
    f32x4 v = *((const f32x4*)(x + (size_t)p * HW_IN + hwbase) + lane);
    hf4 h;
    h[0] = (_Float16)v[0]; h[1] = (_Float16)v[1];
    h[2] = (_Float16)v[2]; h[3] = (_Float16)v[3];
    *(hf4*)&lt[p][lane * 4] = h;
  }
  __syncthreads();

  int gg  = t & 7;
  int hl0 = t >> 3;
#pragma unroll
  for (int j = 0; j < 8; ++j) {
    int hwl = hl0 + j * 32;
    hf8 h;
#pragma unroll
    for (int c = 0; c < 8; ++c) h[c] = lt[gg * 8 + c][hwl];
    *(hf8*)(xt + (size_t)(hwbase + hwl) * 64 + gg * 8) = h;
  }
}

// ---------------------------------------------------------------------------
// Kernel 2: batch-paired gather + MFMA, R9 = R4 single-pass pattern + two
// independent pixel groups per wave, skew-pipelined.
// Diagnosis chain: R4 (bytes-42% -> time-33%), R5/R7 (2x waves -> +27% BW
// but register-impossible cleanly), R8 (misses -14% -> time +6%): the
// kernel is bound by outstanding-miss capacity x latency, not HBM BW.
// time ~ misses x latency / miss-slots: 15.7K misses/CU x 600ns / ~96 ~
// 98us ~ measured 103us. Untried lever: more outstanding misses PER WAVE.
// Each wave owns groups A,B (16 px each); schedule prepB(k), consumeA(k),
// prepA(k+1), consumeB(k): one group's 8KB load cluster is always in
// flight under the other's blend+MFMA. Chains are independent named-var
// dataflows into separate accumulators (unlike R6's cyclic lambda buffer
// the compiler re-serialized). ~158 combined regs -> launch_bounds(256,3),
// 12 waves/CU (~= R4's effective 12.8), in-flight/wave x2.
// ---------------------------------------------------------------------------
#define PREP(SP, K, V0,V1,V2,V3,V4,V5,V6,V7, FX, FY) do {                     \
    float sx_ = SP[(K)*2+0], sy_ = SP[(K)*2+1];                               \
    float bx_ = floorf(sx_), by_ = floorf(sy_);                               \
    FX = sx_-bx_; FY = sy_-by_;                                               \
    int ix0_=(int)bx_, iy0_=(int)by_;                                         \
    int ix1_=min(ix0_+1, W_IN-1), iy1_=min(iy0_+1, H_IN-1);                   \
    ix0_=max(min(ix0_,W_IN-1),0); ix1_=max(ix1_,0);                           \
    iy0_=max(min(iy0_,H_IN-1),0); iy1_=max(iy1_,0);                           \
    int r00_=(iy0_*W_IN+ix0_)*8, r01_=(iy0_*W_IN+ix1_)*8;                     \
    int r10_=(iy1_*W_IN+ix0_)*8, r11_=(iy1_*W_IN+ix1_)*8;                     \
    V0=xt4[r00_+quad]; V1=xt4[r00_+4+quad];                                   \
    V2=xt4[r01_+quad]; V3=xt4[r01_+4+quad];                                   \
    V4=xt4[r10_+quad]; V5=xt4[r10_+4+quad];                                   \
    V6=xt4[r11_+quad]; V7=xt4[r11_+4+quad];                                   \
  } while(0)

#define CONSUME(K, V0,V1,V2,V3,V4,V5,V6,V7, FX, FY, ACC0, ACC1) do {          \
    _Float16 w00_=(_Float16)((1.f-FX)*(1.f-FY));                              \
    _Float16 w01_=(_Float16)(FX*(1.f-FY));                                    \
    _Float16 w10_=(_Float16)((1.f-FX)*FY);                                    \
    _Float16 w11_=(_Float16)(FX*FY);                                          \
    hf8 h00_={w00_,w00_,w00_,w00_,w00_,w00_,w00_,w00_};                       \
    hf8 h01_={w01_,w01_,w01_,w01_,w01_,w01_,w01_,w01_};                       \
    hf8 h10_={w10_,w10_,w10_,w10_,w10_,w10_,w10_,w10_};                       \
    hf8 h11_={w11_,w11_,w11_,w11_,w11_,w11_,w11_,w11_};                       \
    hf8 a0_ = h00_*u4h(V0) + h01_*u4h(V2) + h10_*u4h(V4) + h11_*u4h(V6);      \
    hf8 a1_ = h00_*u4h(V1) + h01_*u4h(V3) + h10_*u4h(V5) + h11_*u4h(V7);      \
    const uint4* wk_ = wbl + (size_t)(K)*256;                                 \
    hf8 b0_=u4h(wk_[0]),  b1_=u4h(wk_[64]);                                   \
    hf8 b2_=u4h(wk_[128]), b3_=u4h(wk_[192]);                                 \
    ACC0[0]=__builtin_amdgcn_mfma_f32_16x16x32_f16(a0_,b0_,ACC0[0],0,0,0);    \
    ACC1[0]=__builtin_amdgcn_mfma_f32_16x16x32_f16(a1_,b0_,ACC1[0],0,0,0);    \
    ACC0[1]=__builtin_amdgcn_mfma_f32_16x16x32_f16(a0_,b1_,ACC0[1],0,0,0);    \
    ACC1[1]=__builtin_amdgcn_mfma_f32_16x16x32_f16(a1_,b1_,ACC1[1],0,0,0);    \
    ACC0[2]=__builtin_amdgcn_mfma_f32_16x16x32_f16(a0_,b2_,ACC0[2],0,0,0);    \
    ACC1[2]=__builtin_amdgcn_mfma_f32_16x16x32_f16(a1_,b2_,ACC1[2],0,0,0);    \
    ACC0[3]=__builtin_amdgcn_mfma_f32_16x16x32_f16(a0_,b3_,ACC0[3],0,0,0);    \
    ACC1[3]=__builtin_amdgcn_mfma_f32_16x16x32_f16(a1_,b3_,ACC1[3],0,0,0);    \
  } while(0)

__global__ __launch_bounds__(256, 3) void mapped_conv_mfma(
    const _Float16* __restrict__ xt,
    const float* __restrict__ weight,   // [COUT][CIN][KK] fp32
    const float* __restrict__ bias,     // [COUT]
    const float* __restrict__ sm,       // [HW_OUT][KK][2] fp32
    float* __restrict__ out) {          // [BB][COUT][HW_OUT] fp32
  __shared__ __align__(16) _Float16 w_lds[KK * COUT * CIN];  // 36 KB

  int t = threadIdx.x;
  // Stage weights: w_lds[(k*64 + o)*32 + c] = W[o][c][k] as f16.
  for (int j = t; j < COUT * CIN * KK; j += 256) {
    unsigned ju = (unsigned)j;
    unsigned o  = ju / 288u;
    unsigned rr = ju % 288u;
    unsigned c  = rr / 9u;
    unsigned k  = rr % 9u;
    w_lds[(k * 64u + o) * 32u + c] = (_Float16)weight[ju];
  }
  __syncthreads();

  int wave = t >> 6;
  int lane = t & 63;
  int m    = lane & 15;   // A-row: pixel; B-col: cout within N-tile
  int quad = lane >> 4;   // channel quarter (A) / k-chunk (B) / row group (C)

  int p0 = blockIdx.x * 128 + wave * 32;   // 1024 blocks x 4 waves x 32 px
  const uint4* xt4 = (const uint4*)xt;

  f32x4 aA0[4] = {{0.f,0.f,0.f,0.f},{0.f,0.f,0.f,0.f},
                  {0.f,0.f,0.f,0.f},{0.f,0.f,0.f,0.f}};
  f32x4 aA1[4] = {{0.f,0.f,0.f,0.f},{0.f,0.f,0.f,0.f},
                  {0.f,0.f,0.f,0.f},{0.f,0.f,0.f,0.f}};
  f32x4 aB0[4] = {{0.f,0.f,0.f,0.f},{0.f,0.f,0.f,0.f},
                  {0.f,0.f,0.f,0.f},{0.f,0.f,0.f,0.f}};
  f32x4 aB1[4] = {{0.f,0.f,0.f,0.f},{0.f,0.f,0.f,0.f},
                  {0.f,0.f,0.f,0.f},{0.f,0.f,0.f,0.f}};

  const float* smpA = sm + (size_t)(p0 + m) * (KK * 2);
  const float* smpB = smpA + 16 * (KK * 2);
  const uint4* wbl = (const uint4*)w_lds + (size_t)(m * 4 + quad);

  uint4 A0,A1,A2,A3,A4,A5,A6,A7;
  uint4 B0,B1,B2,B3,B4,B5,B6,B7;
  float fxA, fyA, fxB, fyB;

  // Skewed two-chain pipeline: one group's 8-load cluster is always in
  // flight under the other group's blend+MFMA.
  PREP(smpA, 0, A0,A1,A2,A3,A4,A5,A6,A7, fxA, fyA);
#pragma unroll 1
  for (int k = 0; k < KK - 1; ++k) {
    PREP(smpB, k, B0,B1,B2,B3,B4,B5,B6,B7, fxB, fyB);
    CONSUME(k, A0,A1,A2,A3,A4,A5,A6,A7, fxA, fyA, aA0, aA1);
    PREP(smpA, k + 1, A0,A1,A2,A3,A4,A5,A6,A7, fxA, fyA);
    CONSUME(k, B0,B1,B2,B3,B4,B5,B6,B7, fxB, fyB, aB0, aB1);
  }
  PREP(smpB, KK - 1, B0,B1,B2,B3,B4,B5,B6,B7, fxB, fyB);
  CONSUME(KK - 1, A0,A1,A2,A3,A4,A5,A6,A7, fxA, fyA, aA0, aA1);
  CONSUME(KK - 1, B0,B1,B2,B3,B4,B5,B6,B7, fxB, fyB, aB0, aB1);

  // Epilogue: lane writes 4 consecutive pixels (rows quad*4..+3) for cout n,
  // both batches, both groups. Plain stores (NT doubled WRITE in R5).
  int hwA = p0 + quad * 4;
  int hwB = hwA + 16;
#pragma unroll
  for (int nt = 0; nt < 4; ++nt) {
    int n = nt * 16 + m;
    float bn = bias[n];
    float4 vA0 = make_float4(aA0[nt][0] + bn, aA0[nt][1] + bn,
                             aA0[nt][2] + bn, aA0[nt][3] + bn);
    float4 vA1 = make_float4(aA1[nt][0] + bn, aA1[nt][1] + bn,
                             aA1[nt][2] + bn, aA1[nt][3] + bn);
    float4 vB0 = make_float4(aB0[nt][0] + bn, aB0[nt][1] + bn,
                             aB0[nt][2] + bn, aB0[nt][3] + bn);
    float4 vB1 = make_float4(aB1[nt][0] + bn, aB1[nt][1] + bn,
                             aB1[nt][2] + bn, aB1[nt][3] + bn);
    *(float4*)(out + (size_t)n * HW_OUT + hwA) = vA0;
    *(float4*)(out + (size_t)(COUT + n) * HW_OUT + hwA) = vA1;
    *(float4*)(out + (size_t)n * HW_OUT + hwB) = vB0;
    *(float4*)(out + (size_t)(COUT + n) * HW_OUT + hwB) = vB1;
  }
}

extern "C" void kernel_launch(void* const* d_in, const int* in_sizes, int n_in,
                              void* d_out, int out_size, void* d_ws, size_t ws_size,
                              hipStream_t stream) {
  const float* x  = (const float*)d_in[0];   // [B][CIN][H*W]
  const float* w  = (const float*)d_in[1];   // [COUT][CIN][KK]
  const float* bs = (const float*)d_in[2];   // [COUT]
  const float* sm = (const float*)d_in[3];   // [OH*OW][KK][2]
  float* out = (float*)d_out;                // [B][COUT][OH*OW]
  _Float16* xt = (_Float16*)d_ws;            // 16 MB scratch: (H*W, B, CIN) f16

  transpose_lds<<<dim3(512), dim3(256), 0, stream>>>(x, xt);
  mapped_conv_mfma<<<dim3(1024), dim3(256), 0, stream>>>(xt, w, bs, sm, out);
}

// Round 11
// 190.990 us; speedup vs baseline: 1.3201x; 1.0008x over previous
//
#include <hip/hip_runtime.h>
#include <hip/hip_fp16.h>

// Problem constants: B=2, CIN=32, COUT=64, K=9, H=256, W=512, OH=256, OW=512
#define HW_IN   131072
#define W_IN    512
#define H_IN    256
#define HW_OUT  131072
#define CIN     32
#define COUT    64
#define KK      9
#define BB      2

typedef _Float16 hf2 __attribute__((ext_vector_type(2)));
typedef _Float16 hf4 __attribute__((ext_vector_type(4)));
typedef _Float16 hf8 __attribute__((ext_vector_type(8)));
typedef float f32x4 __attribute__((ext_vector_type(4)));

static __device__ __forceinline__ hf8 u4h(uint4 u) {
  return __builtin_bit_cast(hf8, u);
}

// ---------------------------------------------------------------------------
// Kernel 1: transpose x (B,CIN,H*W) fp32 -> xt (H*W, B, CIN) f16, via LDS.
// ~5us (R3 single-dispatch run proved the ~85-95us per-round residual is
// FIXED harness overhead). 1KB-contiguous plane-row reads, LDS turn,
// 1KB-contiguous record stores.
// ---------------------------------------------------------------------------
__global__ __launch_bounds__(256) void transpose_lds(
    const float* __restrict__ x, _Float16* __restrict__ xt) {
  __shared__ _Float16 lt[64][260];   // 33.3 KB, row stride 520B
  int t = threadIdx.x;
  int wave = t >> 6, lane = t & 63;
  int hwbase = blockIdx.x * 256;

#pragma unroll
  for (int i = 0; i < 16; ++i) {
    int p = i * 4 + wave;
    f32x4 v = *((const f32x4*)(x + (size_t)p * HW_IN + hwbase) + lane);
    hf4 h;
    h[0] = (_Float16)v[0]; h[1] = (_Float16)v[1];
    h[2] = (_Float16)v[2]; h[3] = (_Float16)v[3];
    *(hf4*)&lt[p][lane * 4] = h;
  }
  __syncthreads();

  int gg  = t & 7;
  int hl0 = t >> 3;
#pragma unroll
  for (int j = 0; j < 8; ++j) {
    int hwl = hl0 + j * 32;
    hf8 h;
#pragma unroll
    for (int c = 0; c < 8; ++c) h[c] = lt[gg * 8 + c][hwl];
    *(hf8*)(xt + (size_t)(hwbase + hwl) * 64 + gg * 8) = h;
  }
}

// ---------------------------------------------------------------------------
// Kernel 2: R10 = R9's skewed two-chain pipeline at 4 blocks/CU.
// R9 measured: VGPR 64 + AGPR 64 = exactly 128 unified regs under a lax
// (256,3) bound -> the (256,4) budget (128) fits the SAME allocation at
// 16 waves/CU (LDS 144KB <= 160KB; grid 1024 = 4 x 256 CUs exactly).
// This stacks R9's per-wave in-flight depth (3.1->3.5 TB/s at 12 waves)
// with R4/R5's wave-count lever (16+ waves -> +0.4 TB/s more). If the
// compiler spills under the exact-fit cap (R5/R7 signature: VGPR collapse,
// WRITE/FETCH inflation), the occupancy x ILP x register triangle is
// exhausted at every corner and R9 is this structure's roofline.
// ---------------------------------------------------------------------------
#define PREP(SP, K, V0,V1,V2,V3,V4,V5,V6,V7, FX, FY) do {                     \
    float sx_ = SP[(K)*2+0], sy_ = SP[(K)*2+1];                               \
    float bx_ = floorf(sx_), by_ = floorf(sy_);                               \
    FX = sx_-bx_; FY = sy_-by_;                                               \
    int ix0_=(int)bx_, iy0_=(int)by_;                                         \
    int ix1_=min(ix0_+1, W_IN-1), iy1_=min(iy0_+1, H_IN-1);                   \
    ix0_=max(min(ix0_,W_IN-1),0); ix1_=max(ix1_,0);                           \
    iy0_=max(min(iy0_,H_IN-1),0); iy1_=max(iy1_,0);                           \
    int r00_=(iy0_*W_IN+ix0_)*8, r01_=(iy0_*W_IN+ix1_)*8;                     \
    int r10_=(iy1_*W_IN+ix0_)*8, r11_=(iy1_*W_IN+ix1_)*8;                     \
    V0=xt4[r00_+quad]; V1=xt4[r00_+4+quad];                                   \
    V2=xt4[r01_+quad]; V3=xt4[r01_+4+quad];                                   \
    V4=xt4[r10_+quad]; V5=xt4[r10_+4+quad];                                   \
    V6=xt4[r11_+quad]; V7=xt4[r11_+4+quad];                                   \
  } while(0)

#define CONSUME(K, V0,V1,V2,V3,V4,V5,V6,V7, FX, FY, ACC0, ACC1) do {          \
    _Float16 w00_=(_Float16)((1.f-FX)*(1.f-FY));                              \
    _Float16 w01_=(_Float16)(FX*(1.f-FY));                                    \
    _Float16 w10_=(_Float16)((1.f-FX)*FY);                                    \
    _Float16 w11_=(_Float16)(FX*FY);                                          \
    hf8 h00_={w00_,w00_,w00_,w00_,w00_,w00_,w00_,w00_};                       \
    hf8 h01_={w01_,w01_,w01_,w01_,w01_,w01_,w01_,w01_};                       \
    hf8 h10_={w10_,w10_,w10_,w10_,w10_,w10_,w10_,w10_};                       \
    hf8 h11_={w11_,w11_,w11_,w11_,w11_,w11_,w11_,w11_};                       \
    hf8 a0_ = h00_*u4h(V0) + h01_*u4h(V2) + h10_*u4h(V4) + h11_*u4h(V6);      \
    hf8 a1_ = h00_*u4h(V1) + h01_*u4h(V3) + h10_*u4h(V5) + h11_*u4h(V7);      \
    const uint4* wk_ = wbl + (size_t)(K)*256;                                 \
    hf8 b0_=u4h(wk_[0]),  b1_=u4h(wk_[64]);                                   \
    hf8 b2_=u4h(wk_[128]), b3_=u4h(wk_[192]);                                 \
    ACC0[0]=__builtin_amdgcn_mfma_f32_16x16x32_f16(a0_,b0_,ACC0[0],0,0,0);    \
    ACC1[0]=__builtin_amdgcn_mfma_f32_16x16x32_f16(a1_,b0_,ACC1[0],0,0,0);    \
    ACC0[1]=__builtin_amdgcn_mfma_f32_16x16x32_f16(a0_,b1_,ACC0[1],0,0,0);    \
    ACC1[1]=__builtin_amdgcn_mfma_f32_16x16x32_f16(a1_,b1_,ACC1[1],0,0,0);    \
    ACC0[2]=__builtin_amdgcn_mfma_f32_16x16x32_f16(a0_,b2_,ACC0[2],0,0,0);    \
    ACC1[2]=__builtin_amdgcn_mfma_f32_16x16x32_f16(a1_,b2_,ACC1[2],0,0,0);    \
    ACC0[3]=__builtin_amdgcn_mfma_f32_16x16x32_f16(a0_,b3_,ACC0[3],0,0,0);    \
    ACC1[3]=__builtin_amdgcn_mfma_f32_16x16x32_f16(a1_,b3_,ACC1[3],0,0,0);    \
  } while(0)

__global__ __launch_bounds__(256, 4) void mapped_conv_mfma(
    const _Float16* __restrict__ xt,
    const float* __restrict__ weight,   // [COUT][CIN][KK] fp32
    const float* __restrict__ bias,     // [COUT]
    const float* __restrict__ sm,       // [HW_OUT][KK][2] fp32
    float* __restrict__ out) {          // [BB][COUT][HW_OUT] fp32
  __shared__ __align__(16) _Float16 w_lds[KK * COUT * CIN];  // 36 KB

  int t = threadIdx.x;
  // Stage weights: w_lds[(k*64 + o)*32 + c] = W[o][c][k] as f16.
  for (int j = t; j < COUT * CIN * KK; j += 256) {
    unsigned ju = (unsigned)j;
    unsigned o  = ju / 288u;
    unsigned rr = ju % 288u;
    unsigned c  = rr / 9u;
    unsigned k  = rr % 9u;
    w_lds[(k * 64u + o) * 32u + c] = (_Float16)weight[ju];
  }
  __syncthreads();

  int wave = t >> 6;
  int lane = t & 63;
  int m    = lane & 15;   // A-row: pixel; B-col: cout within N-tile
  int quad = lane >> 4;   // channel quarter (A) / k-chunk (B) / row group (C)

  int p0 = blockIdx.x * 128 + wave * 32;   // 1024 blocks x 4 waves x 32 px
  const uint4* xt4 = (const uint4*)xt;

  f32x4 aA0[4] = {{0.f,0.f,0.f,0.f},{0.f,0.f,0.f,0.f},
                  {0.f,0.f,0.f,0.f},{0.f,0.f,0.f,0.f}};
  f32x4 aA1[4] = {{0.f,0.f,0.f,0.f},{0.f,0.f,0.f,0.f},
                  {0.f,0.f,0.f,0.f},{0.f,0.f,0.f,0.f}};
  f32x4 aB0[4] = {{0.f,0.f,0.f,0.f},{0.f,0.f,0.f,0.f},
                  {0.f,0.f,0.f,0.f},{0.f,0.f,0.f,0.f}};
  f32x4 aB1[4] = {{0.f,0.f,0.f,0.f},{0.f,0.f,0.f,0.f},
                  {0.f,0.f,0.f,0.f},{0.f,0.f,0.f,0.f}};

  const float* smpA = sm + (size_t)(p0 + m) * (KK * 2);
  const float* smpB = smpA + 16 * (KK * 2);
  const uint4* wbl = (const uint4*)w_lds + (size_t)(m * 4 + quad);

  uint4 A0,A1,A2,A3,A4,A5,A6,A7;
  uint4 B0,B1,B2,B3,B4,B5,B6,B7;
  float fxA, fyA, fxB, fyB;

  // Skewed two-chain pipeline: one group's 8-load cluster is always in
  // flight under the other group's blend+MFMA.
  PREP(smpA, 0, A0,A1,A2,A3,A4,A5,A6,A7, fxA, fyA);
#pragma unroll 1
  for (int k = 0; k < KK - 1; ++k) {
    PREP(smpB, k, B0,B1,B2,B3,B4,B5,B6,B7, fxB, fyB);
    CONSUME(k, A0,A1,A2,A3,A4,A5,A6,A7, fxA, fyA, aA0, aA1);
    PREP(smpA, k + 1, A0,A1,A2,A3,A4,A5,A6,A7, fxA, fyA);
    CONSUME(k, B0,B1,B2,B3,B4,B5,B6,B7, fxB, fyB, aB0, aB1);
  }
  PREP(smpB, KK - 1, B0,B1,B2,B3,B4,B5,B6,B7, fxB, fyB);
  CONSUME(KK - 1, A0,A1,A2,A3,A4,A5,A6,A7, fxA, fyA, aA0, aA1);
  CONSUME(KK - 1, B0,B1,B2,B3,B4,B5,B6,B7, fxB, fyB, aB0, aB1);

  // Epilogue: lane writes 4 consecutive pixels (rows quad*4..+3) for cout n,
  // both batches, both groups. Plain stores (NT doubled WRITE in R5).
  int hwA = p0 + quad * 4;
  int hwB = hwA + 16;
#pragma unroll
  for (int nt = 0; nt < 4; ++nt) {
    int n = nt * 16 + m;
    float bn = bias[n];
    float4 vA0 = make_float4(aA0[nt][0] + bn, aA0[nt][1] + bn,
                             aA0[nt][2] + bn, aA0[nt][3] + bn);
    float4 vA1 = make_float4(aA1[nt][0] + bn, aA1[nt][1] + bn,
                             aA1[nt][2] + bn, aA1[nt][3] + bn);
    float4 vB0 = make_float4(aB0[nt][0] + bn, aB0[nt][1] + bn,
                             aB0[nt][2] + bn, aB0[nt][3] + bn);
    float4 vB1 = make_float4(aB1[nt][0] + bn, aB1[nt][1] + bn,
                             aB1[nt][2] + bn, aB1[nt][3] + bn);
    *(float4*)(out + (size_t)n * HW_OUT + hwA) = vA0;
    *(float4*)(out + (size_t)(COUT + n) * HW_OUT + hwA) = vA1;
    *(float4*)(out + (size_t)n * HW_OUT + hwB) = vB0;
    *(float4*)(out + (size_t)(COUT + n) * HW_OUT + hwB) = vB1;
  }
}

extern "C" void kernel_launch(void* const* d_in, const int* in_sizes, int n_in,
                              void* d_out, int out_size, void* d_ws, size_t ws_size,
                              hipStream_t stream) {
  const float* x  = (const float*)d_in[0];   // [B][CIN][H*W]
  const float* w  = (const float*)d_in[1];   // [COUT][CIN][KK]
  const float* bs = (const float*)d_in[2];   // [COUT]
  const float* sm = (const float*)d_in[3];   // [OH*OW][KK][2]
  float* out = (float*)d_out;                // [B][COUT][OH*OW]
  _Float16* xt = (_Float16*)d_ws;            // 16 MB scratch: (H*W, B, CIN) f16

  transpose_lds<<<dim3(512), dim3(256), 0, stream>>>(x, xt);
  mapped_conv_mfma<<<dim3(1024), dim3(256), 0, stream>>>(xt, w, bs, sm, out);
}